// Round 12
// baseline (162.735 us; speedup 1.0000x reference)
//
#include <hip/hip_runtime.h>
#include <stdint.h>

#define NTOK 4096
#define CDIM 512
#define HEADS 8
#define DHEAD 64
#define PHEAD (NTOK * DHEAD)          // 262144 elems per head per tensor

typedef __bf16 bf16x8 __attribute__((ext_vector_type(8)));
typedef float f32x4 __attribute__((ext_vector_type(4)));

__device__ __forceinline__ unsigned short bfbits(float f) {
    return __builtin_bit_cast(unsigned short, (__bf16)f);   // hw v_cvt on gfx950
}

__device__ __forceinline__ f32x4 mfma32(bf16x8 a, bf16x8 b, f32x4 c) {
    return __builtin_amdgcn_mfma_f32_16x16x32_bf16(a, b, c, 0, 0, 0);
}

// stage 8 fp32 elems as bf16 into LDS (fused cast)
__device__ __forceinline__ void stage8(unsigned short* dst, const float* src) {
    const float4 v0 = *(const float4*)src;
    const float4 v1 = *(const float4*)(src + 4);
    ushort4 o0, o1;
    o0.x = bfbits(v0.x); o0.y = bfbits(v0.y); o0.z = bfbits(v0.z); o0.w = bfbits(v0.w);
    o1.x = bfbits(v1.x); o1.y = bfbits(v1.y); o1.z = bfbits(v1.z); o1.w = bfbits(v1.w);
    *(ushort4*)dst = o0;
    *(ushort4*)(dst + 4) = o1;
}

// ---------------- QKV GEMM (R11 verbatim): 64x128 tiles, 768 blocks = 3/CU ----------------
__global__ __launch_bounds__(256) void gemm_qkv(
    const float* __restrict__ A,            // x  [4096][512] fp32
    const float* __restrict__ Bm,           // Wqkv [1536][512] fp32
    const float* __restrict__ bias,
    const float* __restrict__ scale_p,
    unsigned short* __restrict__ qkv_out)
{
    __shared__ __align__(16) unsigned short smem[64 * 136];   // 17408 B
    unsigned short* lA = smem;              // 64*32
    unsigned short* lB = smem + 2048;       // 128*32

    const int tid = threadIdx.x;
    const int mBase = blockIdx.y * 64, nBase = blockIdx.x * 128;
    const int lane = tid & 63;
    const int w = __builtin_amdgcn_readfirstlane(tid >> 6);
    const int l16 = lane & 15, quad = lane >> 4;
    const int srow = tid >> 2, scol = (tid & 3) * 8;

    f32x4 acc[4][2] = {};

    for (int kt = 0; kt < CDIM; kt += 32) {
        __syncthreads();
        stage8(&lA[srow * 32 + scol], &A[(size_t)(mBase + srow) * CDIM + kt + scol]);
#pragma unroll
        for (int p = 0; p < 2; ++p) {
            const int r = p * 64 + srow;
            stage8(&lB[r * 32 + scol], &Bm[(size_t)(nBase + r) * CDIM + kt + scol]);
        }
        __syncthreads();

        bf16x8 af[4], bfr[2];
#pragma unroll
        for (int i = 0; i < 4; ++i)
            af[i] = *(const bf16x8*)&lA[(i * 16 + l16) * 32 + quad * 8];
#pragma unroll
        for (int j = 0; j < 2; ++j)
            bfr[j] = *(const bf16x8*)&lB[(w * 32 + j * 16 + l16) * 32 + quad * 8];
#pragma unroll
        for (int i = 0; i < 4; ++i)
#pragma unroll
            for (int j = 0; j < 2; ++j)
                acc[i][j] = mfma32(af[i], bfr[j], acc[i][j]);
    }

    const int three = nBase >> 9;
    const float scl = scale_p[0] * 1.44269504f;
    const float mul = (three == 0) ? scl : 1.0f;

    __syncthreads();
#pragma unroll
    for (int i = 0; i < 4; ++i)
#pragma unroll
        for (int j = 0; j < 2; ++j)
#pragma unroll
            for (int r = 0; r < 4; ++r) {
                const int rl = i * 16 + quad * 4 + r;
                const int cl = w * 32 + j * 16 + l16;
                const float v = (acc[i][j][r] + bias[nBase + cl]) * mul;
                smem[rl * 136 + cl] = bfbits(v);
            }
    __syncthreads();

    const size_t base3 = (size_t)three * (PHEAD * HEADS);
    if (three < 2) {
#pragma unroll
        for (int pass = 0; pass < 4; ++pass) {
            const int idx = pass * 256 + tid;
            const int rl16 = idx & 15, qc = (idx >> 4) & 7;
            const int hsel = (idx >> 7) & 1, t16l = (idx >> 8) & 3;
            const uint4 d = *(const uint4*)&smem[(t16l * 16 + rl16) * 136 + hsel * 64 + qc * 8];
            const int hh = ((nBase >> 6) + hsel) & 7;
            const int t16 = (mBase >> 4) + t16l;
            const size_t dst = base3 + (size_t)hh * PHEAD +
                (size_t)(((t16 * 2 + (qc >> 2)) * 64 + (qc & 3) * 16 + rl16) * 8);
            *(uint4*)&qkv_out[dst] = d;
        }
    } else {
#pragma unroll
        for (int pass = 0; pass < 4; ++pass) {
            const int idx = pass * 256 + tid;
            const int l16t = idx & 15, quadt = (idx >> 4) & 3;
            const int dt = (idx >> 6) & 3, k32l = (idx >> 8) & 1, hsel = (idx >> 9) & 1;
            const int col = hsel * 64 + dt * 16 + l16t;
            unsigned short o8[8];
#pragma unroll
            for (int e = 0; e < 4; ++e) {
                o8[e]     = smem[(k32l * 32 + quadt * 4 + e) * 136 + col];
                o8[e + 4] = smem[(k32l * 32 + 16 + quadt * 4 + e) * 136 + col];
            }
            const int hh = ((nBase >> 6) + hsel) & 7;
            const int k32 = (mBase >> 5) + k32l;
            const size_t dst = base3 + (size_t)hh * PHEAD +
                (size_t)(((k32 * 4 + dt) * 64 + quadt * 16 + l16t) * 8);
            *(uint4*)&qkv_out[dst] = *(uint4*)o8;
        }
    }
}

// ---------------- flash v7b: Q-tile 64, 2 key-slices, bulk fp32 partial stores ----------------
// grid (8, 64, 2): x = head (XCD-local), z = slice of 2048 keys. R8-proven math;
// merge via per-slice Opart/lpart buffers (no atomics), combined in gemm_proj_m.
__global__ __launch_bounds__(256, 2) void flash7b_k(
    const unsigned short* __restrict__ qf,
    const unsigned short* __restrict__ kf,
    const unsigned short* __restrict__ vf,
    float* __restrict__ Opart,      // [2][4096][512] fp32 (unnormalized partials)
    float* __restrict__ lpart)      // [2][8][4096] fp32
{
    __shared__ float ldsO[2][64][68];   // 34816 B
    __shared__ float sml[4][64];        // 1024 B

    const int tid = threadIdx.x;
    const int lane = tid & 63;
    const int w = __builtin_amdgcn_readfirstlane(tid >> 6);
    const int l16 = lane & 15, quad = lane >> 4;
    const int h = blockIdx.x, qb = blockIdx.y, ks = blockIdx.z;

    const unsigned short* qh = qf + (size_t)h * PHEAD;
    const unsigned short* kb = kf + (size_t)h * PHEAD + ks * 131072 + w * 32768;
    const unsigned short* vb = vf + (size_t)h * PHEAD + ks * 131072 + w * 32768;

    bf16x8 qfr[4][2];
#pragma unroll
    for (int qt = 0; qt < 4; ++qt)
#pragma unroll
        for (int d2 = 0; d2 < 2; ++d2)
            qfr[qt][d2] = *(const bf16x8*)&qh[((qb * 4 + qt) * 2 + d2) * 512 + lane * 8];

    bf16x8 ones;
#pragma unroll
    for (int j = 0; j < 8; ++j) ones[j] = (__bf16)1.0f;

    f32x4 oacc[4][4] = {};   // [dtile][qtile]: O^T  d=quad*4+r, q=l16
    f32x4 lacc[4] = {};

    bf16x8 kA[4], kB[4];
#pragma unroll
    for (int i = 0; i < 4; ++i)
        kA[i] = *(const bf16x8*)&kb[i * 512 + lane * 8];

    auto body = [&](int g, bf16x8* kuse, bf16x8* kload) {
#pragma unroll
        for (int i = 0; i < 4; ++i)
            kload[i] = *(const bf16x8*)&kb[(g + 1) * 2048 + i * 512 + lane * 8];
        bf16x8 vc[4];
#pragma unroll
        for (int i = 0; i < 4; ++i)
            vc[i] = *(const bf16x8*)&vb[g * 2048 + i * 512 + lane * 8];

        f32x4 s[2][4];
#pragma unroll
        for (int kt = 0; kt < 2; ++kt)
#pragma unroll
            for (int qt = 0; qt < 4; ++qt) {
                f32x4 a = {};
                a = mfma32(kuse[kt * 2 + 0], qfr[qt][0], a);
                a = mfma32(kuse[kt * 2 + 1], qfr[qt][1], a);
                s[kt][qt] = a;
            }

        bf16x8 pf[4];
#pragma unroll
        for (int qt = 0; qt < 4; ++qt) {
            bf16x8 pb;
#pragma unroll
            for (int kt = 0; kt < 2; ++kt)
#pragma unroll
                for (int r = 0; r < 4; ++r)
                    pb[kt * 4 + r] = (__bf16)__builtin_amdgcn_exp2f(s[kt][qt][r]);
            pf[qt] = pb;
            lacc[qt] = mfma32(ones, pb, lacc[qt]);
        }
#pragma unroll
        for (int dt = 0; dt < 4; ++dt)
#pragma unroll
            for (int qt = 0; qt < 4; ++qt)
                oacc[dt][qt] = mfma32(vc[dt], pf[qt], oacc[dt][qt]);
    };

    for (int it = 0; it < 8; ++it) {
        body(it * 2 + 0, kA, kB);
        body(it * 2 + 1, kB, kA);
    }

    // ---- epilogue: 2-buffer LDS merge, then BULK fp32 stores (no atomics) ----
    if (w == 0 || w == 2) {
        const int b = w >> 1;
#pragma unroll
        for (int qt = 0; qt < 4; ++qt)
#pragma unroll
            for (int dt = 0; dt < 4; ++dt)
                *(f32x4*)&ldsO[b][qt * 16 + l16][dt * 16 + quad * 4] = oacc[dt][qt];
    }
    if (quad == 0) {
#pragma unroll
        for (int qt = 0; qt < 4; ++qt) sml[w][qt * 16 + l16] = lacc[qt][0];
    }
    __syncthreads();
    if (w == 1 || w == 3) {
        const int b = w >> 1;
#pragma unroll
        for (int qt = 0; qt < 4; ++qt)
#pragma unroll
            for (int dt = 0; dt < 4; ++dt) {
                float* p = &ldsO[b][qt * 16 + l16][dt * 16 + quad * 4];
                const f32x4 prev = *(const f32x4*)p;
                *(f32x4*)p = prev + oacc[dt][qt];
            }
    }
    __syncthreads();
    {
        const int q = tid >> 2, db = (tid & 3) * 16;
        float* dst = &Opart[(size_t)ks * (NTOK * CDIM) +
                            (size_t)(qb * 64 + q) * CDIM + h * DHEAD + db];
#pragma unroll
        for (int j4 = 0; j4 < 4; ++j4) {
            f32x4 v;
#pragma unroll
            for (int e = 0; e < 4; ++e)
                v[e] = ldsO[0][q][db + j4 * 4 + e] + ldsO[1][q][db + j4 * 4 + e];
            *(f32x4*)(dst + j4 * 4) = v;
        }
        if (tid < 64) {
            const float L = sml[0][tid] + sml[1][tid] + sml[2][tid] + sml[3][tid];
            lpart[(size_t)ks * (HEADS * NTOK) + h * NTOK + qb * 64 + tid] = L;
        }
    }
}

// ---------------- proj GEMM with fused 2-slice merge + normalization ----------------
__global__ __launch_bounds__(256) void gemm_proj_m(
    const float* __restrict__ O0,   // [4096][512] fp32 partial (slice 0)
    const float* __restrict__ O1,   // slice 1
    const float* __restrict__ l0,   // [8][4096]
    const float* __restrict__ l1,
    const float* __restrict__ Bm,   // Wproj [512][512] fp32
    const float* __restrict__ bias,
    float* __restrict__ c_out)
{
    __shared__ __align__(16) unsigned short smem[2 * 64 * 32];  // 8 KB
    unsigned short* lA = smem;
    unsigned short* lB = smem + 2048;

    const int tid = threadIdx.x;
    const int mBase = blockIdx.y * 64, nBase = blockIdx.x * 64;
    const int lane = tid & 63;
    const int w = __builtin_amdgcn_readfirstlane(tid >> 6);
    const int l16 = lane & 15, quad = lane >> 4;
    const int srow = tid >> 2, scol = (tid & 3) * 8;

    f32x4 acc[4] = {};

    for (int kt = 0; kt < CDIM; kt += 32) {
        const int head = kt >> 6;   // uniform per iter (32 | kt, heads 64 wide)
        __syncthreads();
        {
            const int row = mBase + srow;
            const float invl = __builtin_amdgcn_rcpf(
                l0[head * NTOK + row] + l1[head * NTOK + row]);
            const float4 a0 = *(const float4*)&O0[(size_t)row * CDIM + kt + scol];
            const float4 b0 = *(const float4*)&O1[(size_t)row * CDIM + kt + scol];
            const float4 a1 = *(const float4*)&O0[(size_t)row * CDIM + kt + scol + 4];
            const float4 b1 = *(const float4*)&O1[(size_t)row * CDIM + kt + scol + 4];
            ushort4 o0, o1;
            o0.x = bfbits((a0.x + b0.x) * invl); o0.y = bfbits((a0.y + b0.y) * invl);
            o0.z = bfbits((a0.z + b0.z) * invl); o0.w = bfbits((a0.w + b0.w) * invl);
            o1.x = bfbits((a1.x + b1.x) * invl); o1.y = bfbits((a1.y + b1.y) * invl);
            o1.z = bfbits((a1.z + b1.z) * invl); o1.w = bfbits((a1.w + b1.w) * invl);
            *(ushort4*)&lA[srow * 32 + scol] = o0;
            *(ushort4*)&lA[srow * 32 + scol + 4] = o1;
        }
        stage8(&lB[srow * 32 + scol], &Bm[(size_t)(nBase + srow) * CDIM + kt + scol]);
        __syncthreads();

        bf16x8 af[4], bfr;
#pragma unroll
        for (int i = 0; i < 4; ++i)
            af[i] = *(const bf16x8*)&lA[(i * 16 + l16) * 32 + quad * 8];
        bfr = *(const bf16x8*)&lB[(w * 16 + l16) * 32 + quad * 8];
#pragma unroll
        for (int i = 0; i < 4; ++i)
            acc[i] = mfma32(af[i], bfr, acc[i]);
    }

#pragma unroll
    for (int i = 0; i < 4; ++i)
#pragma unroll
        for (int r = 0; r < 4; ++r) {
            const int grow = mBase + i * 16 + quad * 4 + r;
            const int gcol = nBase + w * 16 + l16;
            c_out[(size_t)grow * CDIM + gcol] = acc[i][r] + bias[gcol];
        }
}

// ---------------- Path-B fallbacks (R11 verbatim): flash6 + plain proj ----------------
__global__ __launch_bounds__(256, 4) void flash6_k(
    const unsigned short* __restrict__ qf,
    const unsigned short* __restrict__ kf,
    const unsigned short* __restrict__ vf,
    unsigned short* __restrict__ attn_out)
{
    __shared__ float ldsO[4][32][68];
    __shared__ float sml[4][32];

    const int tid = threadIdx.x;
    const int lane = tid & 63;
    const int w = __builtin_amdgcn_readfirstlane(tid >> 6);
    const int l16 = lane & 15, quad = lane >> 4;
    const int h = blockIdx.x, qb = blockIdx.y;

    const unsigned short* qh = qf + (size_t)h * PHEAD;
    const unsigned short* kb = kf + (size_t)h * PHEAD + w * 65536;
    const unsigned short* vb = vf + (size_t)h * PHEAD + w * 65536;

    bf16x8 qfr[2][2];
#pragma unroll
    for (int qt = 0; qt < 2; ++qt)
#pragma unroll
        for (int d2 = 0; d2 < 2; ++d2)
            qfr[qt][d2] = *(const bf16x8*)&qh[((qb * 2 + qt) * 2 + d2) * 512 + lane * 8];

    bf16x8 ones;
#pragma unroll
    for (int j = 0; j < 8; ++j) ones[j] = (__bf16)1.0f;

    f32x4 oacc[4][2] = {};
    f32x4 lacc[2] = {};

    bf16x8 kA[4], kB[4];
#pragma unroll
    for (int i = 0; i < 4; ++i)
        kA[i] = *(const bf16x8*)&kb[i * 512 + lane * 8];

    auto body = [&](int g, bf16x8* kuse, bf16x8* kload) {
#pragma unroll
        for (int i = 0; i < 4; ++i)
            kload[i] = *(const bf16x8*)&kb[(g + 1) * 2048 + i * 512 + lane * 8];
        bf16x8 vc[4];
#pragma unroll
        for (int i = 0; i < 4; ++i)
            vc[i] = *(const bf16x8*)&vb[g * 2048 + i * 512 + lane * 8];

        f32x4 s[2][2];
#pragma unroll
        for (int kt = 0; kt < 2; ++kt)
#pragma unroll
            for (int qt = 0; qt < 2; ++qt) {
                f32x4 a = {};
                a = mfma32(kuse[kt * 2 + 0], qfr[qt][0], a);
                a = mfma32(kuse[kt * 2 + 1], qfr[qt][1], a);
                s[kt][qt] = a;
            }

        bf16x8 pf[2];
#pragma unroll
        for (int qt = 0; qt < 2; ++qt) {
            bf16x8 pb;
#pragma unroll
            for (int kt = 0; kt < 2; ++kt)
#pragma unroll
                for (int r = 0; r < 4; ++r)
                    pb[kt * 4 + r] = (__bf16)__builtin_amdgcn_exp2f(s[kt][qt][r]);
            pf[qt] = pb;
            lacc[qt] = mfma32(ones, pb, lacc[qt]);
        }
#pragma unroll
        for (int dt = 0; dt < 4; ++dt)
#pragma unroll
            for (int qt = 0; qt < 2; ++qt)
                oacc[dt][qt] = mfma32(vc[dt], pf[qt], oacc[dt][qt]);
    };

    for (int it = 0; it < 16; ++it) {
        body(it * 2 + 0, kA, kB);
        body(it * 2 + 1, kB, kA);
    }

    if (quad == 0) {
#pragma unroll
        for (int qt = 0; qt < 2; ++qt) sml[w][qt * 16 + l16] = lacc[qt][0];
    }
    __syncthreads();
#pragma unroll
    for (int qt = 0; qt < 2; ++qt) {
        const int q = qt * 16 + l16;
#pragma unroll
        for (int dt = 0; dt < 4; ++dt)
            *(f32x4*)&ldsO[w][q][dt * 16 + quad * 4] = oacc[dt][qt];
    }
    __syncthreads();
    {
        const int q = tid >> 3, dseg = (tid & 7) * 8;
        const float L = sml[0][q] + sml[1][q] + sml[2][q] + sml[3][q];
        const float inv = 1.f / L;
        unsigned short o8[8];
#pragma unroll
        for (int i = 0; i < 8; ++i) {
            const float v = ldsO[0][q][dseg + i] + ldsO[1][q][dseg + i] +
                            ldsO[2][q][dseg + i] + ldsO[3][q][dseg + i];
            o8[i] = bfbits(v * inv);
        }
        *(uint4*)&attn_out[(size_t)(qb * 32 + q) * CDIM + h * DHEAD + dseg] = *(uint4*)o8;
    }
}

__global__ __launch_bounds__(256) void gemm_proj(
    const unsigned short* __restrict__ A,
    const float* __restrict__ Bm,
    const float* __restrict__ bias,
    float* __restrict__ c_out)
{
    __shared__ __align__(16) unsigned short smem[2 * 64 * 32];
    unsigned short* lA = smem;
    unsigned short* lB = smem + 2048;

    const int tid = threadIdx.x;
    const int mBase = blockIdx.y * 64, nBase = blockIdx.x * 64;
    const int lane = tid & 63;
    const int w = __builtin_amdgcn_readfirstlane(tid >> 6);
    const int l16 = lane & 15, quad = lane >> 4;
    const int srow = tid >> 2, scol = (tid & 3) * 8;

    f32x4 acc[4] = {};

    for (int kt = 0; kt < CDIM; kt += 32) {
        __syncthreads();
        *(uint4*)&lA[srow * 32 + scol] =
            *(const uint4*)&A[(size_t)(mBase + srow) * CDIM + kt + scol];
        stage8(&lB[srow * 32 + scol], &Bm[(size_t)(nBase + srow) * CDIM + kt + scol]);
        __syncthreads();

        bf16x8 af[4], bfr;
#pragma unroll
        for (int i = 0; i < 4; ++i)
            af[i] = *(const bf16x8*)&lA[(i * 16 + l16) * 32 + quad * 8];
        bfr = *(const bf16x8*)&lB[(w * 16 + l16) * 32 + quad * 8];
#pragma unroll
        for (int i = 0; i < 4; ++i)
            acc[i] = mfma32(af[i], bfr, acc[i]);
    }

#pragma unroll
    for (int i = 0; i < 4; ++i)
#pragma unroll
        for (int r = 0; r < 4; ++r) {
            const int grow = mBase + i * 16 + quad * 4 + r;
            const int gcol = nBase + w * 16 + l16;
            c_out[(size_t)grow * CDIM + gcol] = acc[i][r] + bias[gcol];
        }
}

extern "C" void kernel_launch(void* const* d_in, const int* in_sizes, int n_in,
                              void* d_out, int out_size, void* d_ws, size_t ws_size,
                              hipStream_t stream) {
    const float* x       = (const float*)d_in[0];
    const float* scale_p = (const float*)d_in[3];
    const float* Wqkv    = (const float*)d_in[4];
    const float* bqkv    = (const float*)d_in[5];
    const float* Wproj   = (const float*)d_in[6];
    const float* bproj   = (const float*)d_in[7];
    float* out = (float*)d_out;

    char* ws = (char*)d_ws;
    const size_t OFF_QKV = 0;                         // 12 MB bf16 frag layouts
    const size_t OFF_O0  = 12582912;                  // 8 MB fp32 partial (slice 0)
    const size_t OFF_O1  = OFF_O0 + 8388608;          // 8 MB fp32 partial (slice 1)
    const size_t OFF_L   = OFF_O1 + 8388608;          // 2*8*4096*4 = 256 KB
    const size_t NEED_A  = OFF_L + 262144;            // 28.25 MB (sliced path)
    const size_t NEED_B  = 12582912 + 4194304;        // 16 MB (R11 path)
    if (ws_size < NEED_B) return;

    unsigned short* qkvb = (unsigned short*)(ws + OFF_QKV);

    gemm_qkv<<<dim3(12, 64), 256, 0, stream>>>(x, Wqkv, bqkv, scale_p, qkvb);

    const unsigned short* qfr = qkvb;
    const unsigned short* kfr = qkvb + (size_t)PHEAD * HEADS;
    const unsigned short* vfr = qkvb + (size_t)2 * PHEAD * HEADS;

    if (ws_size >= NEED_A) {
        float* O0 = (float*)(ws + OFF_O0);
        float* O1 = (float*)(ws + OFF_O1);
        float* l0 = (float*)(ws + OFF_L);
        float* l1 = l0 + HEADS * NTOK;
        flash7b_k<<<dim3(8, 64, 2), 256, 0, stream>>>(qfr, kfr, vfr, O0, l0);
        gemm_proj_m<<<dim3(8, 64), 256, 0, stream>>>(O0, O1, l0, l1, Wproj, bproj, out);
    } else {
        unsigned short* attnb = (unsigned short*)(ws + OFF_O0);  // 4 MB bf16
        flash6_k<<<dim3(8, 128), 256, 0, stream>>>(qfr, kfr, vfr, attnb);
        gemm_proj<<<dim3(8, 64), 256, 0, stream>>>(attnb, Wproj, bproj, out);
    }
}